// Round 7
// baseline (1073.358 us; speedup 1.0000x reference)
//
#include <hip/hip_runtime.h>
#include <hip/hip_bf16.h>
#include <math.h>

#define NDIM 512
#define NB   128
#define NMAT 129
#define EPSF 1e-7f
#define MS  ((size_t)262144)   // matrix stride (floats) = 512*512
#define PSTR ((size_t)524288)  // E2 plane stride (floats) = 512*512*2

// workspace layout (float offsets) — L21/U12 live in M's panels (no side buffers)
#define OFF_E   ((size_t)0)                    // 2 planes * 524288 = 1,048,576
#define OFF_WM  ((size_t)1048576)              // 262,144
#define OFF_IPR ((size_t)1310720)              // 65,536
#define OFF_LPR ((size_t)1376256)              // 128
#define OFF_LD  ((size_t)1376384)              // 129
#define OFF_MAT ((size_t)1377792)              // 129*262144 -> total ~134 MB

__device__ __forceinline__ float rdlane(float v, int l) {
  return __uint_as_float((unsigned)__builtin_amdgcn_readlane((int)__float_as_uint(v), l));
}

// ---------- fused Wm + E-IPF (V recomputed inline, identical expressions) ----------
__global__ __launch_bounds__(256) void k_prep(const float* __restrict__ W, const float* __restrict__ Vc,
                                              const float* __restrict__ Ec, float* __restrict__ Wm,
                                              float* __restrict__ E2) {
  int idx = blockIdx.x * 256 + threadIdx.x;   // i*512 + j
  int i = idx >> 9, j = idx & 511;
  float wv = 0.f;
  if (i > j)      wv = 1.f / (1.f + expf(-W[i*NDIM + j]));
  else if (i < j) wv = 1.f / (1.f + expf(-W[j*NDIM + i]));
  Wm[idx] = wv;
  float vi0 = Vc[2*i], vi1 = Vc[2*i+1];
  float mi = fmaxf(vi0, vi1);
  float ei0 = expf(vi0 - mi), ei1 = expf(vi1 - mi);
  float si = ei0 + ei1;
  float A0 = ei0 / si, A1 = ei1 / si;
  float vj0 = Vc[2*j], vj1 = Vc[2*j+1];
  float mj = fmaxf(vj0, vj1);
  float ej0 = expf(vj0 - mj), ej1 = expf(vj1 - mj);
  float sj = ej0 + ej1;
  float B0 = ej0 / sj, B1 = ej1 / sj;
  float4 ec = reinterpret_cast<const float4*>(Ec)[idx];
  float e00 = expf(ec.x), e01 = expf(ec.y), e10 = expf(ec.z), e11 = expf(ec.w);
  float s = e00 + e01 + e10 + e11;
  float inv = 1.f / s;
  e00 *= inv; e01 *= inv; e10 *= inv; e11 *= inv;
  for (int t = 0; t < 10; ++t) {
    float rm0 = e00 + e01 + EPSF, rm1 = e10 + e11 + EPSF;
    float cm0 = e00 + e10 + EPSF, cm1 = e01 + e11 + EPSF;
    float f0 = A0 / rm0, f1 = A1 / rm1;
    e00 *= f0; e01 *= f0; e10 *= f1; e11 *= f1;
    float g0 = B0 / cm0, g1 = B1 / cm1;
    e00 *= g0; e10 *= g0; e01 *= g1; e11 *= g1;
    float ss = e00 + e01 + e10 + e11 + EPSF;
    float iv = 1.f / ss;
    e00 *= iv; e01 *= iv; e10 *= iv; e11 *= iv;
  }
  if (i == j) { e00 = 0.f; e01 = 0.f; e10 = 0.f; e11 = 0.f; }
  e00 = fminf(fmaxf(e00, 0.f), 1.f);
  e01 = fminf(fmaxf(e01, 0.f), 1.f);
  e10 = fminf(fmaxf(e10, 0.f), 1.f);
  e11 = fminf(fmaxf(e11, 0.f), 1.f);
  reinterpret_cast<float2*>(E2)[idx]        = make_float2(e00, e01);  // plane xi=0
  reinterpret_cast<float2*>(E2 + PSTR)[idx] = make_float2(e10, e11);  // plane xi=1
}

// ---------- Pr, invPr, sum(log Pr) per batch (V inline) ----------
__global__ __launch_bounds__(256) void k_Pr(const int* __restrict__ x, const float* __restrict__ Vc,
                                            float* __restrict__ invPr, float* __restrict__ logPr) {
  const int b = blockIdx.x;
  const int tid = threadIdx.x;
  float acc = 0.f;
  for (int ii = tid; ii < NDIM; ii += 256) {
    const int xv = x[b*NDIM + ii];
    float v0 = Vc[2*ii], v1 = Vc[2*ii+1];
    float mx = fmaxf(v0, v1);
    float e0 = expf(v0 - mx), e1 = expf(v1 - mx);
    float s = e0 + e1;
    const float p = xv ? (e1 / s) : (e0 / s);
    invPr[b*NDIM + ii] = 1.f / p;
    acc += logf(p);
  }
  for (int off = 32; off > 0; off >>= 1) acc += __shfl_down(acc, off, 64);
  __shared__ float sw[4];
  if ((tid & 63) == 0) sw[tid >> 6] = acc;
  __syncthreads();
  if (tid == 0) logPr[b] = sw[0] + sw[1] + sw[2] + sw[3];
}

// ---------- build full 512x512 embedded minors: row0 = e0, col0 = 0 ----------
__global__ __launch_bounds__(512) void k_build(const int* __restrict__ x, const float* __restrict__ E2,
                                               const float* __restrict__ Wm, const float* __restrict__ invPr,
                                               float* __restrict__ Mall) {
  const int b = blockIdx.x;
  const int i = blockIdx.y*8 + (threadIdx.x >> 6);
  const int lane = threadIdx.x & 63;
  const int j0 = lane << 3;

  const float4 w0 = *(const float4*)(Wm + (size_t)i*NDIM + j0);
  const float4 w1 = *(const float4*)(Wm + (size_t)i*NDIM + j0 + 4);
  float wp[8];
  if (b < NB) {
    const int   xi   = x[b*NDIM + i];
    const float ipri = invPr[b*NDIM + i];
    const int4  xa = *(const int4*)(x + b*NDIM + j0);
    const int4  xb = *(const int4*)(x + b*NDIM + j0 + 4);
    const float4 pa = *(const float4*)(invPr + b*NDIM + j0);
    const float4 pb = *(const float4*)(invPr + b*NDIM + j0 + 4);
    const float* pl = E2 + (size_t)xi*PSTR + ((size_t)i*NDIM + j0)*2;
    const float4 ea = *(const float4*)(pl);
    const float4 eb = *(const float4*)(pl + 4);
    const float4 ec = *(const float4*)(pl + 8);
    const float4 ed = *(const float4*)(pl + 12);
    wp[0] = w0.x * (xa.x ? ea.y : ea.x) * pa.x;
    wp[1] = w0.y * (xa.y ? ea.w : ea.z) * pa.y;
    wp[2] = w0.z * (xa.z ? eb.y : eb.x) * pa.z;
    wp[3] = w0.w * (xa.w ? eb.w : eb.z) * pa.w;
    wp[4] = w1.x * (xb.x ? ec.y : ec.x) * pb.x;
    wp[5] = w1.y * (xb.y ? ec.w : ec.z) * pb.y;
    wp[6] = w1.z * (xb.z ? ed.y : ed.x) * pb.z;
    wp[7] = w1.w * (xb.w ? ed.w : ed.z) * pb.w;
    #pragma unroll
    for (int k = 0; k < 8; ++k) wp[k] *= ipri;
  } else {
    wp[0]=w0.x; wp[1]=w0.y; wp[2]=w0.z; wp[3]=w0.w;
    wp[4]=w1.x; wp[5]=w1.y; wp[6]=w1.z; wp[7]=w1.w;
  }
  float s = ((wp[0]+wp[1])+(wp[2]+wp[3])) + ((wp[4]+wp[5])+(wp[6]+wp[7]));
  #pragma unroll
  for (int off = 32; off > 0; off >>= 1) s += __shfl_xor(s, off, 64);

  float o[8];
  #pragma unroll
  for (int k = 0; k < 8; ++k) o[k] = -wp[k];
  if (i == 0) {
    #pragma unroll
    for (int k = 0; k < 8; ++k) o[k] = 0.f;
    if (lane == 0) o[0] = 1.f;                    // row 0 = e0
  } else {
    if (lane == 0) o[0] = 0.f;                    // col 0 = 0
    #pragma unroll
    for (int k = 0; k < 8; ++k)
      if (j0 + k == i) o[k] = s;                  // diagonal = full row sum
  }
  float* dst = Mall + (size_t)b*MS + (size_t)i*NDIM + j0;
  *(float4*)(dst)   = make_float4(o[0],o[1],o[2],o[3]);
  *(float4*)(dst+4) = make_float4(o[4],o[5],o[6],o[7]);
}

// ---------- single-wave 64x64 LU of a diagonal block via readlane broadcast ----------
template<int KK>
struct WFact {
  static __device__ __forceinline__ void run(float (&a)[64], const int lane,
                                             float& mypiv, float& myrec) {
    const float piv = rdlane(a[KK], KK);
    const float rec = 1.0f / piv;
    if (lane == KK) { mypiv = piv; myrec = rec; }
    if (lane > KK) {
      const float l = a[KK] * rec;
      a[KK] = l;
      #pragma unroll
      for (int c = KK + 1; c < 64; ++c)
        a[c] -= l * rdlane(a[c], KK);
    }
    WFact<KK + 1>::run(a, lane, mypiv, myrec);
  }
};
template<>
struct WFact<64> {
  static __device__ __forceinline__ void run(float (&)[64], int, float&, float&) {}
};

// ---------- L21 row triangular solve: a <- a * U11^{-1} ----------
template<int C>
struct SolveStep {
  static __device__ __forceinline__ void run(float (&a)[64], const float (*T)[68]) {
    float acc = a[C];
    #pragma unroll
    for (int p = 0; p < C; ++p)
      acc -= a[p] * T[C][p];                  // T[C][p] = U11[p][C], broadcast read
    a[C] = acc * T[C][66];                    // * 1/U11[C][C]
    SolveStep<C + 1>::run(a, T);
  }
};
template<>
struct SolveStep<64> {
  static __device__ __forceinline__ void run(float (&)[64], const float (*)[68]) {}
};

// ---------- 128-wide superpanel, register-disciplined: no thread holds >64-float array ----------
// Phases: A diag0 LU | B L21_0 solve->M | C strip TRSM->LDS | D' strip update (coop GEMM,
// A re-read from M) | E diag1 LU (from M) | F L21_1 solve->M | H' K=128 TRSM (u0->M, volatile
// re-read for correction). Per-element op order identical to round-5 flow.
__global__ __launch_bounds__(512) void k_panel128(float* __restrict__ Mall,
                                                  float* __restrict__ logdets, int k0, int ncols) {
  const int b = blockIdx.x;
  float* __restrict__ M = Mall + (size_t)b*MS;
  const int t = threadIdx.x;
  const int m = NDIM - k0;            // 512,384,256,128
  __shared__ float T0[64][68];        // factored diag0 (transposed); recip diag at [r][66]
  __shared__ float T1[64][68];        // phases C/D': U12strip; phases E+: factored diag1
  __shared__ float Ls2[64][68];       // Ls2[c][r] = L21strip[r][c] (rows 64..128, cols 0..64)

  float acc_ld = 0.f;

  // upfront: every row thread loads its cols k0..k0+64
  float a[64];
  if (t < m) {
    const float* row = M + (size_t)(k0+t)*NDIM + k0;
    #pragma unroll
    for (int c4 = 0; c4 < 16; ++c4) {
      float4 v = *(const float4*)(row + c4*4);
      a[c4*4+0]=v.x; a[c4*4+1]=v.y; a[c4*4+2]=v.z; a[c4*4+3]=v.w;
    }
  }

  // A: wave0 factors diag0
  if (t < 64) {
    float mypiv = 1.f, myrec = 1.f;
    WFact<0>::run(a, t, mypiv, myrec);
    #pragma unroll
    for (int c = 0; c < 64; ++c) T0[c][t] = a[c];
    T0[t][66] = myrec;
    float v = logf(fabsf(mypiv));
    #pragma unroll
    for (int off = 32; off > 0; off >>= 1) v += __shfl_down(v, off, 64);
    if (t == 0) acc_ld = v;
  }
  __syncthreads();                    // T0 ready

  // B: L21 block-0 solve; write to M immediately (final); rows 64..127 stash Ls2
  if (t >= 64 && t < m) {
    SolveStep<0>::run(a, T0);
    float* row = M + (size_t)(k0+t)*NDIM + k0;
    #pragma unroll
    for (int c4 = 0; c4 < 16; ++c4)
      *(float4*)(row + c4*4) = make_float4(a[c4*4],a[c4*4+1],a[c4*4+2],a[c4*4+3]);
    if (t < 128) {
      #pragma unroll
      for (int c = 0; c < 64; ++c) Ls2[c][t-64] = a[c];
    }
  }
  // C: wave0 TRSM for the 64 strip cols -> T1 (as U12strip); a is dead for wave0
  if (t < 64) {
    const int col = k0 + 64 + t;
    float u[64];
    #pragma unroll
    for (int r = 0; r < 64; ++r) u[r] = M[(size_t)(k0+r)*NDIM + col];
    #pragma unroll
    for (int p = 0; p < 63; ++p) {
      const float lv = u[p];
      #pragma unroll
      for (int kk = p+1; kk < 64; ++kk) u[kk] -= T0[p][kk] * lv;
    }
    #pragma unroll
    for (int r = 0; r < 64; ++r) T1[r][t] = u[r];
  }
  __syncthreads();                    // U12strip + Ls2 + B's M-writes visible

  // D': strip update as cooperative GEMM over rows 64..m-1, cols k0+64..k0+128.
  // A (=L21_0) re-read from M (L1/L2-hot, 8-lane broadcast); p ascending (same order).
  {
    const int npass = (m - 64) >> 6;
    const int rloc = t >> 3;          // 0..63
    const int col0 = (t & 7) * 8;
    for (int pass = 0; pass < npass; ++pass) {
      const int row = 64 + pass*64 + rloc;
      float* crow = M + (size_t)(k0+row)*NDIM + (k0+64+col0);
      const float* arow = M + (size_t)(k0+row)*NDIM + k0;
      float4 cA = *(const float4*)(crow);
      float4 cB = *(const float4*)(crow + 4);
      float c8[8] = {cA.x,cA.y,cA.z,cA.w,cB.x,cB.y,cB.z,cB.w};
      #pragma unroll
      for (int p = 0; p < 64; ++p) {
        const float ap = arow[p];
        #pragma unroll
        for (int j = 0; j < 8; ++j) c8[j] -= ap * T1[p][col0+j];
      }
      *(float4*)(crow)     = make_float4(c8[0],c8[1],c8[2],c8[3]);
      *(float4*)(crow + 4) = make_float4(c8[4],c8[5],c8[6],c8[7]);
    }
  }
  __syncthreads();                    // strip updated in M; U12strip consumed

  // E: wave0 factors diag1 from M (updated by D' pass 0); t>=128 prefetch L21_1 rows
  float s[64];
  if (t < 64) {
    const float* row = M + (size_t)(k0+64+t)*NDIM + (k0+64);
    #pragma unroll
    for (int c4 = 0; c4 < 16; ++c4) {
      float4 v = *(const float4*)(row + c4*4);
      s[c4*4+0]=v.x; s[c4*4+1]=v.y; s[c4*4+2]=v.z; s[c4*4+3]=v.w;
    }
    float mypiv = 1.f, myrec = 1.f;
    WFact<0>::run(s, t, mypiv, myrec);
    #pragma unroll
    for (int c = 0; c < 64; ++c) T1[c][t] = s[c];
    T1[t][66] = myrec;
    float v = logf(fabsf(mypiv));
    #pragma unroll
    for (int off = 32; off > 0; off >>= 1) v += __shfl_down(v, off, 64);
    if (t == 0) acc_ld += v;
  } else if (t >= 128 && t < m) {
    const float* row = M + (size_t)(k0+t)*NDIM + (k0+64);
    #pragma unroll
    for (int c4 = 0; c4 < 16; ++c4) {
      float4 v = *(const float4*)(row + c4*4);
      s[c4*4+0]=v.x; s[c4*4+1]=v.y; s[c4*4+2]=v.z; s[c4*4+3]=v.w;
    }
  }
  __syncthreads();                    // T1 (factored diag1) ready

  // F: L21 block-1 solve (rows >=128), write to M (final)
  if (t >= 128 && t < m) {
    SolveStep<0>::run(s, T1);
    float* row = M + (size_t)(k0+t)*NDIM + (k0+64);
    #pragma unroll
    for (int c4 = 0; c4 < 16; ++c4)
      *(float4*)(row + c4*4) = make_float4(s[c4*4],s[c4*4+1],s[c4*4+2],s[c4*4+3]);
  }

  // H': K=128 TRSM for remaining cols; disjoint rows from F, runs concurrently
  if (t < ncols) {
    const int col = k0 + 128 + t;
    {
      float u[64];
      #pragma unroll
      for (int r = 0; r < 64; ++r) u[r] = M[(size_t)(k0+r)*NDIM + col];
      #pragma unroll
      for (int p = 0; p < 63; ++p) {
        const float lv = u[p];
        #pragma unroll
        for (int kk = p+1; kk < 64; ++kk) u[kk] -= T0[p][kk] * lv;
      }
      #pragma unroll
      for (int r = 1; r < 64; ++r) M[(size_t)(k0+r)*NDIM + col] = u[r];  // row 0 unchanged
    }
    // u dead. Correction re-reads u0 via volatile (blocks store-to-load forwarding
    // that would keep u alive -> 128-reg pressure -> the round-5/6 spill).
    float v2[64];
    #pragma unroll
    for (int r = 0; r < 64; ++r) v2[r] = M[(size_t)(k0+64+r)*NDIM + col];
    const volatile float* Mv = M;
    #pragma unroll
    for (int p = 0; p < 64; ++p) {
      const float up = Mv[(size_t)(k0+p)*NDIM + col];
      #pragma unroll
      for (int r = 0; r < 64; ++r) v2[r] -= Ls2[p][r] * up;
    }
    #pragma unroll
    for (int p = 0; p < 63; ++p) {
      const float lv = v2[p];
      #pragma unroll
      for (int kk = p+1; kk < 64; ++kk) v2[kk] -= T1[p][kk] * lv;
    }
    #pragma unroll
    for (int r = 0; r < 64; ++r) M[(size_t)(k0+64+r)*NDIM + col] = v2[r];
  }

  if (t == 0) logdets[b] = (k0 == 0) ? acc_ld : (logdets[b] + acc_ld);
}

// ---------- trailing update: C -= L21 * U12, 64x64 tile, K=128 in two staged halves ----------
__global__ __launch_bounds__(256, 4) void k_gemm2(float* __restrict__ Mall, int k0) {
  const int b = blockIdx.x;
  float* __restrict__ M = Mall + (size_t)b*MS;
  __shared__ float As[64][68];     // As[p][r] = L21[r][p]
  __shared__ float Bs[64][68];     // Bs[p][c] = U12[p][c]
  const int tid = threadIdx.x;
  const int tx = tid & 15, ty = tid >> 4;
  const int rowbase = 128 + blockIdx.y*64;
  const int colbase = 128 + blockIdx.z*64;
  float* Crow = M + (size_t)(k0+rowbase+ty*4)*NDIM + (k0+colbase+tx*4);
  float4 c0 = *(float4*)(Crow + 0*NDIM);
  float4 c1 = *(float4*)(Crow + 1*NDIM);
  float4 c2 = *(float4*)(Crow + 2*NDIM);
  float4 c3 = *(float4*)(Crow + 3*NDIM);
  #pragma unroll
  for (int i = 0; i < 4; ++i) {
    const int q = tid + 256*i, qr = q >> 4, qf = q & 15;
    const float4 va = *(const float4*)&M[(size_t)(k0+rowbase+qr)*NDIM + k0 + qf*4];
    As[qf*4+0][qr]=va.x; As[qf*4+1][qr]=va.y; As[qf*4+2][qr]=va.z; As[qf*4+3][qr]=va.w;
    *(float4*)&Bs[qr][qf*4] = *(const float4*)&M[(size_t)(k0+qr)*NDIM + (k0+colbase) + qf*4];
  }
  __syncthreads();
  float4 ra[4], rb[4];
  #pragma unroll
  for (int i = 0; i < 4; ++i) {
    const int q = tid + 256*i, qr = q >> 4, qf = q & 15;
    ra[i] = *(const float4*)&M[(size_t)(k0+rowbase+qr)*NDIM + k0 + 64 + qf*4];
    rb[i] = *(const float4*)&M[(size_t)(k0+64+qr)*NDIM + (k0+colbase) + qf*4];
  }
  #pragma unroll
  for (int p = 0; p < 64; ++p) {
    const float4 av = *(const float4*)&As[p][ty*4];
    const float4 bv = *(const float4*)&Bs[p][tx*4];
    c0.x -= av.x*bv.x; c0.y -= av.x*bv.y; c0.z -= av.x*bv.z; c0.w -= av.x*bv.w;
    c1.x -= av.y*bv.x; c1.y -= av.y*bv.y; c1.z -= av.y*bv.z; c1.w -= av.y*bv.w;
    c2.x -= av.z*bv.x; c2.y -= av.z*bv.y; c2.z -= av.z*bv.z; c2.w -= av.z*bv.w;
    c3.x -= av.w*bv.x; c3.y -= av.w*bv.y; c3.z -= av.w*bv.z; c3.w -= av.w*bv.w;
  }
  __syncthreads();
  #pragma unroll
  for (int i = 0; i < 4; ++i) {
    const int q = tid + 256*i, qr = q >> 4, qf = q & 15;
    As[qf*4+0][qr]=ra[i].x; As[qf*4+1][qr]=ra[i].y; As[qf*4+2][qr]=ra[i].z; As[qf*4+3][qr]=ra[i].w;
    *(float4*)&Bs[qr][qf*4] = rb[i];
  }
  __syncthreads();
  #pragma unroll
  for (int p = 0; p < 64; ++p) {
    const float4 av = *(const float4*)&As[p][ty*4];
    const float4 bv = *(const float4*)&Bs[p][tx*4];
    c0.x -= av.x*bv.x; c0.y -= av.x*bv.y; c0.z -= av.x*bv.z; c0.w -= av.x*bv.w;
    c1.x -= av.y*bv.x; c1.y -= av.y*bv.y; c1.z -= av.y*bv.z; c1.w -= av.y*bv.w;
    c2.x -= av.z*bv.x; c2.y -= av.z*bv.y; c2.z -= av.z*bv.z; c2.w -= av.z*bv.w;
    c3.x -= av.w*bv.x; c3.y -= av.w*bv.y; c3.z -= av.w*bv.z; c3.w -= av.w*bv.w;
  }
  *(float4*)(Crow + 0*NDIM) = c0;
  *(float4*)(Crow + 1*NDIM) = c1;
  *(float4*)(Crow + 2*NDIM) = c2;
  *(float4*)(Crow + 3*NDIM) = c3;
}

// ---------- final combine ----------
__global__ void k_final(const float* __restrict__ logPr, const float* __restrict__ logdets,
                        float* __restrict__ out) {
  int t = threadIdx.x;
  if (t < NB) out[t] = logPr[t] + logdets[t] - logdets[NB];
}

extern "C" void kernel_launch(void* const* d_in, const int* in_sizes, int n_in,
                              void* d_out, int out_size, void* d_ws, size_t ws_size,
                              hipStream_t stream) {
  const int*   x  = (const int*)  d_in[0];
  const float* W  = (const float*)d_in[1];
  const float* Vc = (const float*)d_in[2];
  const float* Ec = (const float*)d_in[3];
  float* out = (float*)d_out;
  float* ws  = (float*)d_ws;
  (void)in_sizes; (void)n_in; (void)out_size; (void)ws_size;  // needs ~134 MiB of ws

  float* Mat = ws + OFF_MAT;
  float* Ld  = ws + OFF_LD;

  k_prep<<<1024, 256, 0, stream>>>(W, Vc, Ec, ws + OFF_WM, ws + OFF_E);
  k_Pr  <<<NB,   256, 0, stream>>>(x, Vc, ws + OFF_IPR, ws + OFF_LPR);
  dim3 gb(NMAT, 64);
  k_build<<<gb, 512, 0, stream>>>(x, ws + OFF_E, ws + OFF_WM, ws + OFF_IPR, Mat);

  for (int S = 0; S < 4; ++S) {
    const int k0 = S*128;
    const int ncols = NDIM - k0 - 128;
    k_panel128<<<NMAT, 512, 0, stream>>>(Mat, Ld, k0, ncols);
    if (ncols > 0) {
      const int nt = ncols/64;
      dim3 gg(NMAT, nt, nt);
      k_gemm2<<<gg, 256, 0, stream>>>(Mat, k0);
    }
  }
  k_final<<<1, 128, 0, stream>>>(ws + OFF_LPR, Ld, out);
}

// Round 8
// 672.878 us; speedup vs baseline: 1.5952x; 1.5952x over previous
//
#include <hip/hip_runtime.h>
#include <hip/hip_bf16.h>
#include <math.h>

#define NDIM 512
#define NB   128
#define NMAT 129
#define EPSF 1e-7f
#define MS  ((size_t)262144)   // matrix stride (floats) = 512*512
#define PSTR ((size_t)524288)  // E2 plane stride (floats) = 512*512*2

// workspace layout (float offsets) — L21/U12 live in M's panels (no side buffers)
#define OFF_E   ((size_t)0)                    // 2 planes * 524288 = 1,048,576
#define OFF_WM  ((size_t)1048576)              // 262,144
#define OFF_IPR ((size_t)1310720)              // 65,536
#define OFF_LPR ((size_t)1376256)              // 128
#define OFF_LD  ((size_t)1376384)              // 129
#define OFF_MAT ((size_t)1377792)              // 129*262144 -> total ~134 MB

__device__ __forceinline__ float rdlane(float v, int l) {
  return __uint_as_float((unsigned)__builtin_amdgcn_readlane((int)__float_as_uint(v), l));
}

// ---------- fused Wm + E-IPF (V recomputed inline, identical expressions) ----------
__global__ __launch_bounds__(256) void k_prep(const float* __restrict__ W, const float* __restrict__ Vc,
                                              const float* __restrict__ Ec, float* __restrict__ Wm,
                                              float* __restrict__ E2) {
  int idx = blockIdx.x * 256 + threadIdx.x;   // i*512 + j
  int i = idx >> 9, j = idx & 511;
  float wv = 0.f;
  if (i > j)      wv = 1.f / (1.f + expf(-W[i*NDIM + j]));
  else if (i < j) wv = 1.f / (1.f + expf(-W[j*NDIM + i]));
  Wm[idx] = wv;
  float vi0 = Vc[2*i], vi1 = Vc[2*i+1];
  float mi = fmaxf(vi0, vi1);
  float ei0 = expf(vi0 - mi), ei1 = expf(vi1 - mi);
  float si = ei0 + ei1;
  float A0 = ei0 / si, A1 = ei1 / si;
  float vj0 = Vc[2*j], vj1 = Vc[2*j+1];
  float mj = fmaxf(vj0, vj1);
  float ej0 = expf(vj0 - mj), ej1 = expf(vj1 - mj);
  float sj = ej0 + ej1;
  float B0 = ej0 / sj, B1 = ej1 / sj;
  float4 ec = reinterpret_cast<const float4*>(Ec)[idx];
  float e00 = expf(ec.x), e01 = expf(ec.y), e10 = expf(ec.z), e11 = expf(ec.w);
  float s = e00 + e01 + e10 + e11;
  float inv = 1.f / s;
  e00 *= inv; e01 *= inv; e10 *= inv; e11 *= inv;
  for (int t = 0; t < 10; ++t) {
    float rm0 = e00 + e01 + EPSF, rm1 = e10 + e11 + EPSF;
    float cm0 = e00 + e10 + EPSF, cm1 = e01 + e11 + EPSF;
    float f0 = A0 / rm0, f1 = A1 / rm1;
    e00 *= f0; e01 *= f0; e10 *= f1; e11 *= f1;
    float g0 = B0 / cm0, g1 = B1 / cm1;
    e00 *= g0; e10 *= g0; e01 *= g1; e11 *= g1;
    float ss = e00 + e01 + e10 + e11 + EPSF;
    float iv = 1.f / ss;
    e00 *= iv; e01 *= iv; e10 *= iv; e11 *= iv;
  }
  if (i == j) { e00 = 0.f; e01 = 0.f; e10 = 0.f; e11 = 0.f; }
  e00 = fminf(fmaxf(e00, 0.f), 1.f);
  e01 = fminf(fmaxf(e01, 0.f), 1.f);
  e10 = fminf(fmaxf(e10, 0.f), 1.f);
  e11 = fminf(fmaxf(e11, 0.f), 1.f);
  reinterpret_cast<float2*>(E2)[idx]        = make_float2(e00, e01);  // plane xi=0
  reinterpret_cast<float2*>(E2 + PSTR)[idx] = make_float2(e10, e11);  // plane xi=1
}

// ---------- Pr, invPr, sum(log Pr) per batch (V inline) ----------
__global__ __launch_bounds__(256) void k_Pr(const int* __restrict__ x, const float* __restrict__ Vc,
                                            float* __restrict__ invPr, float* __restrict__ logPr) {
  const int b = blockIdx.x;
  const int tid = threadIdx.x;
  float acc = 0.f;
  for (int ii = tid; ii < NDIM; ii += 256) {
    const int xv = x[b*NDIM + ii];
    float v0 = Vc[2*ii], v1 = Vc[2*ii+1];
    float mx = fmaxf(v0, v1);
    float e0 = expf(v0 - mx), e1 = expf(v1 - mx);
    float s = e0 + e1;
    const float p = xv ? (e1 / s) : (e0 / s);
    invPr[b*NDIM + ii] = 1.f / p;
    acc += logf(p);
  }
  for (int off = 32; off > 0; off >>= 1) acc += __shfl_down(acc, off, 64);
  __shared__ float sw[4];
  if ((tid & 63) == 0) sw[tid >> 6] = acc;
  __syncthreads();
  if (tid == 0) logPr[b] = sw[0] + sw[1] + sw[2] + sw[3];
}

// ---------- build full 512x512 embedded minors: row0 = e0, col0 = 0 ----------
__global__ __launch_bounds__(512) void k_build(const int* __restrict__ x, const float* __restrict__ E2,
                                               const float* __restrict__ Wm, const float* __restrict__ invPr,
                                               float* __restrict__ Mall) {
  const int b = blockIdx.x;
  const int i = blockIdx.y*8 + (threadIdx.x >> 6);
  const int lane = threadIdx.x & 63;
  const int j0 = lane << 3;

  const float4 w0 = *(const float4*)(Wm + (size_t)i*NDIM + j0);
  const float4 w1 = *(const float4*)(Wm + (size_t)i*NDIM + j0 + 4);
  float wp[8];
  if (b < NB) {
    const int   xi   = x[b*NDIM + i];
    const float ipri = invPr[b*NDIM + i];
    const int4  xa = *(const int4*)(x + b*NDIM + j0);
    const int4  xb = *(const int4*)(x + b*NDIM + j0 + 4);
    const float4 pa = *(const float4*)(invPr + b*NDIM + j0);
    const float4 pb = *(const float4*)(invPr + b*NDIM + j0 + 4);
    const float* pl = E2 + (size_t)xi*PSTR + ((size_t)i*NDIM + j0)*2;
    const float4 ea = *(const float4*)(pl);
    const float4 eb = *(const float4*)(pl + 4);
    const float4 ec = *(const float4*)(pl + 8);
    const float4 ed = *(const float4*)(pl + 12);
    wp[0] = w0.x * (xa.x ? ea.y : ea.x) * pa.x;
    wp[1] = w0.y * (xa.y ? ea.w : ea.z) * pa.y;
    wp[2] = w0.z * (xa.z ? eb.y : eb.x) * pa.z;
    wp[3] = w0.w * (xa.w ? eb.w : eb.z) * pa.w;
    wp[4] = w1.x * (xb.x ? ec.y : ec.x) * pb.x;
    wp[5] = w1.y * (xb.y ? ec.w : ec.z) * pb.y;
    wp[6] = w1.z * (xb.z ? ed.y : ed.x) * pb.z;
    wp[7] = w1.w * (xb.w ? ed.w : ed.z) * pb.w;
    #pragma unroll
    for (int k = 0; k < 8; ++k) wp[k] *= ipri;
  } else {
    wp[0]=w0.x; wp[1]=w0.y; wp[2]=w0.z; wp[3]=w0.w;
    wp[4]=w1.x; wp[5]=w1.y; wp[6]=w1.z; wp[7]=w1.w;
  }
  float s = ((wp[0]+wp[1])+(wp[2]+wp[3])) + ((wp[4]+wp[5])+(wp[6]+wp[7]));
  #pragma unroll
  for (int off = 32; off > 0; off >>= 1) s += __shfl_xor(s, off, 64);

  float o[8];
  #pragma unroll
  for (int k = 0; k < 8; ++k) o[k] = -wp[k];
  if (i == 0) {
    #pragma unroll
    for (int k = 0; k < 8; ++k) o[k] = 0.f;
    if (lane == 0) o[0] = 1.f;                    // row 0 = e0
  } else {
    if (lane == 0) o[0] = 0.f;                    // col 0 = 0
    #pragma unroll
    for (int k = 0; k < 8; ++k)
      if (j0 + k == i) o[k] = s;                  // diagonal = full row sum
  }
  float* dst = Mall + (size_t)b*MS + (size_t)i*NDIM + j0;
  *(float4*)(dst)   = make_float4(o[0],o[1],o[2],o[3]);
  *(float4*)(dst+4) = make_float4(o[4],o[5],o[6],o[7]);
}

// ---------- single-wave 64x64 LU of a diagonal block via readlane broadcast ----------
template<int KK>
struct WFact {
  static __device__ __forceinline__ void run(float (&a)[64], const int lane,
                                             float& mypiv, float& myrec) {
    const float piv = rdlane(a[KK], KK);
    const float rec = 1.0f / piv;
    if (lane == KK) { mypiv = piv; myrec = rec; }
    if (lane > KK) {
      const float l = a[KK] * rec;
      a[KK] = l;
      #pragma unroll
      for (int c = KK + 1; c < 64; ++c)
        a[c] -= l * rdlane(a[c], KK);
    }
    WFact<KK + 1>::run(a, lane, mypiv, myrec);
  }
};
template<>
struct WFact<64> {
  static __device__ __forceinline__ void run(float (&)[64], int, float&, float&) {}
};

// ---------- L21 row triangular solve: a <- a * U11^{-1} ----------
template<int C>
struct SolveStep {
  static __device__ __forceinline__ void run(float (&a)[64], const float (*T)[68]) {
    float acc = a[C];
    #pragma unroll
    for (int p = 0; p < C; ++p)
      acc -= a[p] * T[C][p];                  // T[C][p] = U11[p][C], broadcast read
    a[C] = acc * T[C][66];                    // * 1/U11[C][C]
    SolveStep<C + 1>::run(a, T);
  }
};
template<>
struct SolveStep<64> {
  static __device__ __forceinline__ void run(float (&)[64], const float (*)[68]) {}
};

// ---------- panel A: diag0 LU + L21_0 solve -> M + K=64 TRSM over ALL trailing cols ----------
// round-3 k_panel shape: at most ONE 64-float array live per thread (a, then u).
__global__ __launch_bounds__(512) void k_panelA(float* __restrict__ Mall,
                                                float* __restrict__ logdets, int k0) {
  const int b = blockIdx.x;
  float* __restrict__ M = Mall + (size_t)b*MS;
  const int t = threadIdx.x;
  const int m = NDIM - k0;          // 512,384,256,128
  const int mrem = m - 64;
  __shared__ float T[64][68];       // factored diag0 transposed; recip at [r][66]

  float a[64];
  if (t < m) {
    const float* row = M + (size_t)(k0+t)*NDIM + k0;
    #pragma unroll
    for (int c4 = 0; c4 < 16; ++c4) {
      float4 v = *(const float4*)(row + c4*4);
      a[c4*4+0]=v.x; a[c4*4+1]=v.y; a[c4*4+2]=v.z; a[c4*4+3]=v.w;
    }
  }
  if (t < 64) {
    float mypiv = 1.f, myrec = 1.f;
    WFact<0>::run(a, t, mypiv, myrec);
    #pragma unroll
    for (int c = 0; c < 64; ++c) T[c][t] = a[c];
    T[t][66] = myrec;
    float v = logf(fabsf(mypiv));
    #pragma unroll
    for (int off = 32; off > 0; off >>= 1) v += __shfl_down(v, off, 64);
    if (t == 0) logdets[b] = (k0 == 0) ? v : (logdets[b] + v);
  }
  __syncthreads();

  if (mrem > 0) {
    // L21_0 rows: solve and write straight into M (final values)
    if (t >= 64 && t < m) {
      SolveStep<0>::run(a, T);
      float* row = M + (size_t)(k0+t)*NDIM + k0;
      #pragma unroll
      for (int c4 = 0; c4 < 16; ++c4)
        *(float4*)(row + c4*4) = make_float4(a[c4*4],a[c4*4+1],a[c4*4+2],a[c4*4+3]);
    }
    // U12: K=64 TRSM for ALL trailing cols (strip + far); a dead before u born
    if (t < mrem) {
      const int col = k0 + 64 + t;
      float u[64];
      #pragma unroll
      for (int r = 0; r < 64; ++r) u[r] = M[(size_t)(k0+r)*NDIM + col];
      #pragma unroll
      for (int p = 0; p < 63; ++p) {
        const float lv = u[p];
        #pragma unroll
        for (int kk = p+1; kk < 64; ++kk) u[kk] -= T[p][kk] * lv;
      }
      #pragma unroll
      for (int r = 1; r < 64; ++r) M[(size_t)(k0+r)*NDIM + col] = u[r];  // row 0 unchanged
    }
  }
}

// ---------- strip update: C[64..m, 64..128) -= L21_0 * U12strip (K=64, one 64x64 tile/block) ----------
__global__ __launch_bounds__(256, 4) void k_strip(float* __restrict__ Mall, int k0) {
  const int b = blockIdx.x;
  float* __restrict__ M = Mall + (size_t)b*MS;
  __shared__ float As[64][68];     // As[p][r] = L21_0[r][p]
  __shared__ float Bs[64][68];     // Bs[p][c] = U12strip[p][c]
  const int tid = threadIdx.x;
  const int tx = tid & 15, ty = tid >> 4;
  const int rowbase = 64 + blockIdx.y*64;   // panel-local row
  #pragma unroll
  for (int i = 0; i < 4; ++i) {
    const int q = tid + 256*i, qr = q >> 4, qf = q & 15;
    const float4 va = *(const float4*)&M[(size_t)(k0+rowbase+qr)*NDIM + k0 + qf*4];
    As[qf*4+0][qr]=va.x; As[qf*4+1][qr]=va.y; As[qf*4+2][qr]=va.z; As[qf*4+3][qr]=va.w;
    *(float4*)&Bs[qr][qf*4] = *(const float4*)&M[(size_t)(k0+qr)*NDIM + (k0+64) + qf*4];
  }
  float* Crow = M + (size_t)(k0+rowbase+ty*4)*NDIM + (k0+64+tx*4);
  float4 c0 = *(float4*)(Crow + 0*NDIM);
  float4 c1 = *(float4*)(Crow + 1*NDIM);
  float4 c2 = *(float4*)(Crow + 2*NDIM);
  float4 c3 = *(float4*)(Crow + 3*NDIM);
  __syncthreads();
  #pragma unroll
  for (int p = 0; p < 64; ++p) {
    const float4 av = *(const float4*)&As[p][ty*4];
    const float4 bv = *(const float4*)&Bs[p][tx*4];
    c0.x -= av.x*bv.x; c0.y -= av.x*bv.y; c0.z -= av.x*bv.z; c0.w -= av.x*bv.w;
    c1.x -= av.y*bv.x; c1.y -= av.y*bv.y; c1.z -= av.y*bv.z; c1.w -= av.y*bv.w;
    c2.x -= av.z*bv.x; c2.y -= av.z*bv.y; c2.z -= av.z*bv.z; c2.w -= av.z*bv.w;
    c3.x -= av.w*bv.x; c3.y -= av.w*bv.y; c3.z -= av.w*bv.z; c3.w -= av.w*bv.w;
  }
  *(float4*)(Crow + 0*NDIM) = c0;
  *(float4*)(Crow + 1*NDIM) = c1;
  *(float4*)(Crow + 2*NDIM) = c2;
  *(float4*)(Crow + 3*NDIM) = c3;
}

// ---------- panel B: diag1 LU + L21_1 solve -> M + far-col 3-stage TRSM ----------
// same register discipline: one 64-float array live (s, then u). u0 re-read coalesced
// from M (written by k_panelA, previous launch -> clean cross-launch dependency).
__global__ __launch_bounds__(512) void k_panelB(float* __restrict__ Mall,
                                                float* __restrict__ logdets, int k0, int ncols) {
  const int b = blockIdx.x;
  float* __restrict__ M = Mall + (size_t)b*MS;
  const int t = threadIdx.x;
  const int m = NDIM - k0;          // 512,384,256,128
  __shared__ float T[64][68];       // factored diag1 transposed; recip at [r][66]
  __shared__ float Ls2[64][68];     // Ls2[p][r] = L21strip[r][p] = M[k0+64+r][k0+p]

  float s[64];
  if (t < 64) {                     // diag1 row (strip-updated by k_strip)
    const float* row = M + (size_t)(k0+64+t)*NDIM + (k0+64);
    #pragma unroll
    for (int c4 = 0; c4 < 16; ++c4) {
      float4 v = *(const float4*)(row + c4*4);
      s[c4*4+0]=v.x; s[c4*4+1]=v.y; s[c4*4+2]=v.z; s[c4*4+3]=v.w;
    }
  } else if (t < 128) {             // stage Ls2 (L21_0 rows 64..127, written by panelA)
    const int r = t - 64;
    const float* row = M + (size_t)(k0+64+r)*NDIM + k0;
    #pragma unroll
    for (int c = 0; c < 64; ++c) Ls2[c][r] = row[c];
  } else if (t < m) {               // L21_1 raw row (strip-updated)
    const float* row = M + (size_t)(k0+t)*NDIM + (k0+64);
    #pragma unroll
    for (int c4 = 0; c4 < 16; ++c4) {
      float4 v = *(const float4*)(row + c4*4);
      s[c4*4+0]=v.x; s[c4*4+1]=v.y; s[c4*4+2]=v.z; s[c4*4+3]=v.w;
    }
  }

  if (t < 64) {
    float mypiv = 1.f, myrec = 1.f;
    WFact<0>::run(s, t, mypiv, myrec);
    #pragma unroll
    for (int c = 0; c < 64; ++c) T[c][t] = s[c];
    T[t][66] = myrec;
    float v = logf(fabsf(mypiv));
    #pragma unroll
    for (int off = 32; off > 0; off >>= 1) v += __shfl_down(v, off, 64);
    if (t == 0) logdets[b] += v;
  }
  __syncthreads();                  // T + Ls2 ready

  // L21_1 rows: solve and write into M (final)
  if (t >= 128 && t < m) {
    SolveStep<0>::run(s, T);
    float* row = M + (size_t)(k0+t)*NDIM + (k0+64);
    #pragma unroll
    for (int c4 = 0; c4 < 16; ++c4)
      *(float4*)(row + c4*4) = make_float4(s[c4*4],s[c4*4+1],s[c4*4+2],s[c4*4+3]);
  }

  // far cols: u1 -= L21strip*u0 (u0 coalesced from M), then K=64 TRSM vs T
  if (t < ncols) {
    const int col = k0 + 128 + t;
    float u[64];
    #pragma unroll
    for (int r = 0; r < 64; ++r) u[r] = M[(size_t)(k0+64+r)*NDIM + col];
    #pragma unroll
    for (int p = 0; p < 64; ++p) {
      const float up = M[(size_t)(k0+p)*NDIM + col];   // U12_0[p][col], coalesced, L2-hot
      #pragma unroll
      for (int r = 0; r < 64; ++r) u[r] -= Ls2[p][r] * up;
    }
    #pragma unroll
    for (int p = 0; p < 63; ++p) {
      const float lv = u[p];
      #pragma unroll
      for (int kk = p+1; kk < 64; ++kk) u[kk] -= T[p][kk] * lv;
    }
    #pragma unroll
    for (int r = 0; r < 64; ++r) M[(size_t)(k0+64+r)*NDIM + col] = u[r];
  }
}

// ---------- trailing update: C -= L21 * U12, 64x64 tile, K=128 in two staged halves ----------
__global__ __launch_bounds__(256, 4) void k_gemm2(float* __restrict__ Mall, int k0) {
  const int b = blockIdx.x;
  float* __restrict__ M = Mall + (size_t)b*MS;
  __shared__ float As[64][68];     // As[p][r] = L21[r][p]
  __shared__ float Bs[64][68];     // Bs[p][c] = U12[p][c]
  const int tid = threadIdx.x;
  const int tx = tid & 15, ty = tid >> 4;
  const int rowbase = 128 + blockIdx.y*64;
  const int colbase = 128 + blockIdx.z*64;
  float* Crow = M + (size_t)(k0+rowbase+ty*4)*NDIM + (k0+colbase+tx*4);
  float4 c0 = *(float4*)(Crow + 0*NDIM);
  float4 c1 = *(float4*)(Crow + 1*NDIM);
  float4 c2 = *(float4*)(Crow + 2*NDIM);
  float4 c3 = *(float4*)(Crow + 3*NDIM);
  #pragma unroll
  for (int i = 0; i < 4; ++i) {
    const int q = tid + 256*i, qr = q >> 4, qf = q & 15;
    const float4 va = *(const float4*)&M[(size_t)(k0+rowbase+qr)*NDIM + k0 + qf*4];
    As[qf*4+0][qr]=va.x; As[qf*4+1][qr]=va.y; As[qf*4+2][qr]=va.z; As[qf*4+3][qr]=va.w;
    *(float4*)&Bs[qr][qf*4] = *(const float4*)&M[(size_t)(k0+qr)*NDIM + (k0+colbase) + qf*4];
  }
  __syncthreads();
  float4 ra[4], rb[4];
  #pragma unroll
  for (int i = 0; i < 4; ++i) {
    const int q = tid + 256*i, qr = q >> 4, qf = q & 15;
    ra[i] = *(const float4*)&M[(size_t)(k0+rowbase+qr)*NDIM + k0 + 64 + qf*4];
    rb[i] = *(const float4*)&M[(size_t)(k0+64+qr)*NDIM + (k0+colbase) + qf*4];
  }
  #pragma unroll
  for (int p = 0; p < 64; ++p) {
    const float4 av = *(const float4*)&As[p][ty*4];
    const float4 bv = *(const float4*)&Bs[p][tx*4];
    c0.x -= av.x*bv.x; c0.y -= av.x*bv.y; c0.z -= av.x*bv.z; c0.w -= av.x*bv.w;
    c1.x -= av.y*bv.x; c1.y -= av.y*bv.y; c1.z -= av.y*bv.z; c1.w -= av.y*bv.w;
    c2.x -= av.z*bv.x; c2.y -= av.z*bv.y; c2.z -= av.z*bv.z; c2.w -= av.z*bv.w;
    c3.x -= av.w*bv.x; c3.y -= av.w*bv.y; c3.z -= av.w*bv.z; c3.w -= av.w*bv.w;
  }
  __syncthreads();
  #pragma unroll
  for (int i = 0; i < 4; ++i) {
    const int q = tid + 256*i, qr = q >> 4, qf = q & 15;
    As[qf*4+0][qr]=ra[i].x; As[qf*4+1][qr]=ra[i].y; As[qf*4+2][qr]=ra[i].z; As[qf*4+3][qr]=ra[i].w;
    *(float4*)&Bs[qr][qf*4] = rb[i];
  }
  __syncthreads();
  #pragma unroll
  for (int p = 0; p < 64; ++p) {
    const float4 av = *(const float4*)&As[p][ty*4];
    const float4 bv = *(const float4*)&Bs[p][tx*4];
    c0.x -= av.x*bv.x; c0.y -= av.x*bv.y; c0.z -= av.x*bv.z; c0.w -= av.x*bv.w;
    c1.x -= av.y*bv.x; c1.y -= av.y*bv.y; c1.z -= av.y*bv.z; c1.w -= av.y*bv.w;
    c2.x -= av.z*bv.x; c2.y -= av.z*bv.y; c2.z -= av.z*bv.z; c2.w -= av.z*bv.w;
    c3.x -= av.w*bv.x; c3.y -= av.w*bv.y; c3.z -= av.w*bv.z; c3.w -= av.w*bv.w;
  }
  *(float4*)(Crow + 0*NDIM) = c0;
  *(float4*)(Crow + 1*NDIM) = c1;
  *(float4*)(Crow + 2*NDIM) = c2;
  *(float4*)(Crow + 3*NDIM) = c3;
}

// ---------- final combine ----------
__global__ void k_final(const float* __restrict__ logPr, const float* __restrict__ logdets,
                        float* __restrict__ out) {
  int t = threadIdx.x;
  if (t < NB) out[t] = logPr[t] + logdets[t] - logdets[NB];
}

extern "C" void kernel_launch(void* const* d_in, const int* in_sizes, int n_in,
                              void* d_out, int out_size, void* d_ws, size_t ws_size,
                              hipStream_t stream) {
  const int*   x  = (const int*)  d_in[0];
  const float* W  = (const float*)d_in[1];
  const float* Vc = (const float*)d_in[2];
  const float* Ec = (const float*)d_in[3];
  float* out = (float*)d_out;
  float* ws  = (float*)d_ws;
  (void)in_sizes; (void)n_in; (void)out_size; (void)ws_size;  // needs ~134 MiB of ws

  float* Mat = ws + OFF_MAT;
  float* Ld  = ws + OFF_LD;

  k_prep<<<1024, 256, 0, stream>>>(W, Vc, Ec, ws + OFF_WM, ws + OFF_E);
  k_Pr  <<<NB,   256, 0, stream>>>(x, Vc, ws + OFF_IPR, ws + OFF_LPR);
  dim3 gb(NMAT, 64);
  k_build<<<gb, 512, 0, stream>>>(x, ws + OFF_E, ws + OFF_WM, ws + OFF_IPR, Mat);

  for (int S = 0; S < 4; ++S) {
    const int k0 = S*128;
    const int m = NDIM - k0;
    const int ncols = m - 128;
    k_panelA<<<NMAT, 512, 0, stream>>>(Mat, Ld, k0);
    dim3 gs(NMAT, (m - 64)/64);
    k_strip<<<gs, 256, 0, stream>>>(Mat, k0);
    k_panelB<<<NMAT, 512, 0, stream>>>(Mat, Ld, k0, ncols);
    if (ncols > 0) {
      const int nt = ncols/64;
      dim3 gg(NMAT, nt, nt);
      k_gemm2<<<gg, 256, 0, stream>>>(Mat, k0);
    }
  }
  k_final<<<1, 128, 0, stream>>>(ws + OFF_LPR, Ld, out);
}